// Round 20
// baseline (90.607 us; speedup 1.0000x reference)
//
#include <hip/hip_runtime.h>
#include <math.h>

// LinearCatVAE loss on MI355X.
// Psi = Helmert basis => Psi products are diag + prefix scans.
// R16/R18 (79.9us, best): burst mega (1 barrier, W-frag stream, bf16
// partials), split-4. Mega plateau confirmed (3 structures x occ 19-37%
// all 54-57us -> latency/request bound).
// R19: launch fusion via last-block ticket pattern (6 -> 4 launches):
// gram_reduce+neumann fused (16-block kernel, last block runs neumann);
// fixup absorbs the final reduction (last of 512 blocks sums part_out in
// fixed order -> deterministic). prep2 zeroes the tickets (stream-ordered).

#define LOG2PI_F 1.8378770664093453f

typedef short  v8s    __attribute__((ext_vector_type(8)));
typedef short  v4s    __attribute__((ext_vector_type(4)));
typedef float  f32x4v __attribute__((ext_vector_type(4)));
typedef float  f32x4u __attribute__((ext_vector_type(4), aligned(4)));
typedef float  f32x2u __attribute__((ext_vector_type(2), aligned(4)));

// ---- workspace offsets (floats) ----
#define OFF_A     0          // 2048
#define OFF_C     2048       // 2048
#define OFF_G     4096       // 4096
#define OFF_MINV  8192       // 4096
#define OFF_MISC  12288      // 64
#define OFF_WFRAG 12352      // 131072 (512KB)
#define OFF_ZPART 143424     // bf16 4*8192*64 = 1048576 float-slots
#define OFF_GPART OFF_ZPART  // alias: gpart (131072 floats) dead before mega
#define OFF_TPART 1192000    // 1048576 float-slots
#define OFF_SCAN  2240576    // 262144
#define OFF_PART  2502720    // 512 doubles = 1024 floats
#define OFF_CNT   2503744    // 2 ints
#define OFF_END   2503746    // ~10 MB

__device__ inline float red16(float v){
#pragma unroll
  for (int m = 1; m < 16; m <<= 1) v += __shfl_xor(v, m, 16);
  return v;
}
__device__ inline float bf2f(short s){
  union { unsigned u; float f; } v;
  v.u = ((unsigned)(unsigned short)s) << 16;
  return v.f;
}

// ------- PREP2 (fused): 0-63 wenceff->frags, 64-95 wdtgram->frags+gpart,
//                        96-103 coef; blk96 zeroes the tickets --------------
__global__ __launch_bounds__(256) void prep2_kernel(const float* __restrict__ Psi,
    const float* __restrict__ Wenc, const float* __restrict__ Wdec,
    float* __restrict__ a_ws, float* __restrict__ c_ws,
    short* __restrict__ fr, float* __restrict__ gparts, int* __restrict__ cnt){
  __shared__ __align__(16) float shm[64 * 68];
  const int tid = threadIdx.x;
  const int blk = blockIdx.x;
  if (blk >= 96){
    if (blk == 96 && tid == 0){ cnt[0] = 0; cnt[1] = 0; }
    // coef: a[e]=Psi[e][e], c[e]=-Psi[e][e+1]
    int e = (blk - 96) * 256 + tid;
    float a = 0.f, c = 0.f;
    if (e < 1999){
      f32x2u v = *(const f32x2u*)(Psi + (size_t)e * 2001);
      a = v[0]; c = -v[1];
    }
    a_ws[e] = a;
    c_ws[e] = c;
    return;
  }
  if (blk < 64){
    // wenceff: row k of Wenc@Psi via exclusive scan; write frag planes 0/1
    float* scan = shm;
    const int k = blk;
    const float* wrow = Wenc + (size_t)k * 1999;
    int base = tid * 8;
    float w[8], sloc[8], av[8], cv[8];
    float run = 0.f;
#pragma unroll
    for (int u = 0; u < 8; ++u){
      int e = base + u;
      bool valid = (e < 1999);
      float wv = valid ? wrow[e] : 0.f;
      if (valid){
        f32x2u v = *(const f32x2u*)(Psi + (size_t)e * 2001);
        av[u] = v[0]; cv[u] = -v[1];
      } else { av[u] = 0.f; cv[u] = 0.f; }
      w[u] = wv;
      sloc[u] = run;
      run += cv[u] * wv;
    }
    scan[tid] = run;
    __syncthreads();
    for (int off = 1; off < 256; off <<= 1){
      float y = (tid >= off) ? scan[tid - off] : 0.f;
      __syncthreads();
      scan[tid] += y;
      __syncthreads();
    }
    float excl = scan[tid] - run;
    union { __bf16 b[8]; v8s s; } pk;
#pragma unroll
    for (int u = 0; u < 8; ++u){
      int e = base + u;
      float val = (e < 2000) ? (av[u] * w[u] - (excl + sloc[u])) : 0.f;
      pk.b[u] = (__bf16)val;
    }
    int sc = base >> 6;
    int r  = base & 63;
    int kh = r >> 5;
    int kg = r & 31;
    int tid_m = ((k >> 4) << 6) | ((kg >> 3) << 4) | (k & 15);
    *(v8s*)(fr + (size_t)sc * 8192 + kh * 2048 + tid_m * 8) = pk.s;
    return;
  }
  // wdtgram: chunk sc of Wdec -> frag planes 2/3 + gram partial
  auto Ws = (float(*)[68])shm;
  const int sc = blk - 64;
  const int j0 = sc * 64;
#pragma unroll
  for (int i = 0; i < 16; ++i){
    int e = tid + i * 256;
    int j = e >> 6, kk = e & 63;
    Ws[j][kk] = (j0 + j < 1999) ? Wdec[(size_t)(j0 + j) * 64 + kk] : 0.f;
  }
  __syncthreads();
  {
    const int bcol = ((tid >> 6) << 4) | (tid & 15);
    const int kg = ((tid >> 4) & 3) * 8;
    union { __bf16 b[8]; v8s s; } p2, p3;
#pragma unroll
    for (int u = 0; u < 8; ++u){
      p2.b[u] = (__bf16)Ws[kg + u][bcol];
      p3.b[u] = (__bf16)Ws[32 + kg + u][bcol];
    }
    short* o = fr + (size_t)sc * 8192 + tid * 8;
    *(v8s*)(o + 4096) = p2.s;
    *(v8s*)(o + 6144) = p3.s;
  }
  int p = tid & 63;
  int qb = (tid >> 6) * 16;
  float acc[16] = {};
  for (int jj = 0; jj < 64; ++jj){
    float wp = Ws[jj][p];
    const float4 q0 = *(const float4*)&Ws[jj][qb];
    const float4 q1 = *(const float4*)&Ws[jj][qb + 4];
    const float4 q2 = *(const float4*)&Ws[jj][qb + 8];
    const float4 q3 = *(const float4*)&Ws[jj][qb + 12];
    acc[0]  = fmaf(wp, q0.x, acc[0]);  acc[1]  = fmaf(wp, q0.y, acc[1]);
    acc[2]  = fmaf(wp, q0.z, acc[2]);  acc[3]  = fmaf(wp, q0.w, acc[3]);
    acc[4]  = fmaf(wp, q1.x, acc[4]);  acc[5]  = fmaf(wp, q1.y, acc[5]);
    acc[6]  = fmaf(wp, q1.z, acc[6]);  acc[7]  = fmaf(wp, q1.w, acc[7]);
    acc[8]  = fmaf(wp, q2.x, acc[8]);  acc[9]  = fmaf(wp, q2.y, acc[9]);
    acc[10] = fmaf(wp, q2.z, acc[10]); acc[11] = fmaf(wp, q2.w, acc[11]);
    acc[12] = fmaf(wp, q3.x, acc[12]); acc[13] = fmaf(wp, q3.y, acc[13]);
    acc[14] = fmaf(wp, q3.z, acc[14]); acc[15] = fmaf(wp, q3.w, acc[15]);
  }
  float* gp = gparts + (size_t)sc * 4096 + (size_t)p * 64 + qb;
#pragma unroll
  for (int u = 0; u < 4; ++u){
    float4 o; o.x = acc[4*u]; o.y = acc[4*u+1]; o.z = acc[4*u+2]; o.w = acc[4*u+3];
    *(float4*)&gp[4*u] = o;
  }
}

// ---- GRAMNEU: 16 blocks reduce gparts->G; LAST block runs neumann ----
__global__ __launch_bounds__(256) void gramneu_kernel(const float* __restrict__ gparts,
    const float* __restrict__ vlv, const float* __restrict__ lss,
    float* __restrict__ Gws, float* __restrict__ Minv, float* __restrict__ misc,
    int* __restrict__ cnt){
  __shared__ float As[64][65];
  __shared__ float A2s[64][65];
  __shared__ double dred[4][3];
  __shared__ int lastf;
  const int tid = threadIdx.x;
  {
    int e = blockIdx.x * 256 + tid;
    float s = 0.f;
#pragma unroll
    for (int p = 0; p < 32; ++p) s += gparts[(size_t)p * 4096 + e];
    Gws[e] = s;
  }
  __threadfence();
  if (tid == 0){
    int old = atomicAdd(&cnt[0], 1);
    lastf = (old == 15);
  }
  __syncthreads();
  if (!lastf) return;
  __threadfence();   // acquire: all G writes visible
  // ---- neumann body (Minv + logdet, Neumann truncated at A^2) ----
  float var = expf(lss[0]);
  for (int e = tid; e < 4096; e += 256){
    int i = e >> 6;
    As[i][e & 63] = expf(vlv[i]) * Gws[e] / var;
  }
  __syncthreads();
  for (int e = tid; e < 4096; e += 256){
    int i = e >> 6, j = e & 63;
    float s = 0.f;
    for (int q = 0; q < 64; ++q) s = fmaf(As[i][q], As[q][j], s);
    A2s[i][j] = s;
  }
  __syncthreads();
  double t1 = 0, t2 = 0, t3 = 0;
  for (int e = tid; e < 4096; e += 256){
    int i = e >> 6, j = e & 63;
    if (i == j){ t1 += (double)As[i][i]; t2 += (double)A2s[i][i]; }
    t3 += (double)A2s[i][j] * (double)As[j][i];
  }
#pragma unroll
  for (int m = 1; m < 64; m <<= 1){
    t1 += __shfl_xor(t1, m, 64); t2 += __shfl_xor(t2, m, 64); t3 += __shfl_xor(t3, m, 64);
  }
  int wid = tid >> 6;
  if ((tid & 63) == 0){ dred[wid][0] = t1; dred[wid][1] = t2; dred[wid][2] = t3; }
  __syncthreads();
  for (int e = tid; e < 4096; e += 256){
    int i = e >> 6, j = e & 63;
    float v = ((i == j) ? 1.f : 0.f) - As[i][j] + A2s[i][j];
    Minv[e] = v * expf(vlv[j]);
  }
  if (tid == 0){
    double tr1 = 0, tr2 = 0, tr3 = 0;
    for (int w2 = 0; w2 < 4; ++w2){
      tr1 += dred[w2][0]; tr2 += dred[w2][1]; tr3 += dred[w2][2];
    }
    misc[0] = (float)(1999.0 * (double)lss[0] + tr1 - tr2 / 2.0 + tr3 / 3.0);
  }
}

// ---------------- MEGA "burst": whole-tile stage, ONE barrier --------------
// 2048 blocks x 256 threads; split = bid&3 (8 chunks of 64 cols);
// rowblk = bid>>2 -> 16 rows. LDS ~38KB -> 4 blocks/CU natural.
__global__ __launch_bounds__(256) void mega_kernel(
    const float* __restrict__ x, const float* __restrict__ eta,
    const short* __restrict__ wfrag,
    const float* __restrict__ a_ws, const float* __restrict__ c_ws,
    short* __restrict__ zpart, short* __restrict__ tpart,
    float* __restrict__ scanw)
{
  __shared__ float lutlg[128];
  __shared__ __align__(16) float a_lds[512];
  __shared__ __align__(16) float c_lds[512];
  __shared__ __align__(16) __bf16 At[16][520];   // 1040B row stride
  __shared__ __align__(16) __bf16 Ae[16][520];
  auto z_l = (float(*)[68])((unsigned char*)At);             // epilogue overlay
  auto t_l = (float(*)[68])((unsigned char*)At + 4352);

  const int tid = threadIdx.x;
  const int split = blockIdx.x & 3;
  const int rowblk = blockIdx.x >> 2;
  const int b0 = rowblk * 16;
  const int ch0 = split * 8;
  const int cb0 = split * 512;
  if (tid < 128) lutlg[tid] = lgammaf((float)(tid + 1));
  for (int i = tid; i < 512; i += 256){ a_lds[i] = a_ws[cb0 + i]; c_lds[i] = c_ws[cb0 + i]; }

  const int lrow = tid >> 4;
  const int sl   = tid & 15;
  const int lq4  = sl * 4;
  const int wid  = tid >> 6, lan = tid & 63;
  const int arow = lan & 15;
  const int bcol = wid * 16 + (lan & 15);
  const int kgrp = (lan >> 4) * 8;

  f32x4v accz = {0.f, 0.f, 0.f, 0.f}, acct = {0.f, 0.f, 0.f, 0.f};
  float carry = 0.f, mOn = -3.0e38f, sOn = 0.f;
  float xdot = 0.f, sx = 0.f, sgl = 0.f, e2 = 0.f;

  const float* xs_base = x   + (size_t)(b0 + lrow) * 2000 + cb0 + lq4;
  const float* es_base = eta + (size_t)(b0 + lrow) * 1999 + cb0 + lq4;
  const short* fr_base = wfrag + (size_t)ch0 * 8192 + (size_t)tid * 8;
  const bool lastSplit = (split == 3);

  // ---- burst-load all 8 chunks of x and eta (all loads in flight) ----
  float xv[8][4], ev[8][4];
#pragma unroll
  for (int c = 0; c < 8; ++c){
    const float* xp = xs_base + c * 64;
    if (!(lastSplit && c == 7)){
      f32x4v v = *(const f32x4v*)xp;
      xv[c][0] = v[0]; xv[c][1] = v[1]; xv[c][2] = v[2]; xv[c][3] = v[3];
    } else {
#pragma unroll
      for (int u = 0; u < 4; ++u){
        int cc = cb0 + c * 64 + lq4 + u;
        xv[c][u] = (cc < 2000) ? xp[u] : 0.f;
      }
    }
  }
#pragma unroll
  for (int c = 0; c < 8; ++c){
    const float* ep = es_base + c * 64;
    if (!(lastSplit && c == 7)){
      f32x4u v = *(const f32x4u*)ep;
      ev[c][0] = v[0]; ev[c][1] = v[1]; ev[c][2] = v[2]; ev[c][3] = v[3];
    } else {
#pragma unroll
      for (int u = 0; u < 4; ++u){
        int cc = cb0 + c * 64 + lq4 + u;
        ev[c][u] = (cc < 1999) ? ep[u] : 0.f;
      }
    }
  }
  v8s WF0[2], WF1[2], WD0[2], WD1[2];
  {
    const short* fb = fr_base;
    WF0[0] = *(const v8s*)(fb);
    WF1[0] = *(const v8s*)(fb + 2048);
    WD0[0] = *(const v8s*)(fb + 4096);
    WD1[0] = *(const v8s*)(fb + 6144);
  }
  // ---- convert + stage whole tile ----
#pragma unroll
  for (int c = 0; c < 8; ++c){
    union { __bf16 b[4]; unsigned long long q; } cx, ce;
#pragma unroll
    for (int u = 0; u < 4; ++u){
      cx.b[u] = (__bf16)__logf(xv[c][u] + 1.f);
      ce.b[u] = (__bf16)ev[c][u];
    }
    *(unsigned long long*)&At[lrow][c * 64 + lq4] = cx.q;
    *(unsigned long long*)&Ae[lrow][c * 64 + lq4] = ce.q;
  }
  __syncthreads();   // the ONLY staging barrier

  // ---- 8 barrier-free chunk steps ----
#pragma unroll
  for (int c = 0; c < 8; ++c){
    if (c + 1 < 8){
      const short* fb = fr_base + (size_t)(c + 1) * 8192;
      WF0[(c + 1) & 1] = *(const v8s*)(fb);
      WF1[(c + 1) & 1] = *(const v8s*)(fb + 2048);
      WD0[(c + 1) & 1] = *(const v8s*)(fb + 4096);
      WD1[(c + 1) & 1] = *(const v8s*)(fb + 6144);
    }
    {
      const int cb = c * 64;
      v8s ax0 = *(const v8s*)&At[arow][cb + kgrp];
      v8s ax1 = *(const v8s*)&At[arow][cb + 32 + kgrp];
      v8s ae0 = *(const v8s*)&Ae[arow][cb + kgrp];
      v8s ae1 = *(const v8s*)&Ae[arow][cb + 32 + kgrp];
      accz = __builtin_amdgcn_mfma_f32_16x16x32_bf16(ax0, WF0[c & 1], accz, 0, 0, 0);
      accz = __builtin_amdgcn_mfma_f32_16x16x32_bf16(ax1, WF1[c & 1], accz, 0, 0, 0);
      acct = __builtin_amdgcn_mfma_f32_16x16x32_bf16(ae0, WD0[c & 1], acct, 0, 0, 0);
      acct = __builtin_amdgcn_mfma_f32_16x16x32_bf16(ae1, WD1[c & 1], acct, 0, 0, 0);
    }
    {
      const int j0g = (ch0 + c) * 64;
      const int jl  = c * 64;
      const bool guard = lastSplit && (c == 7);
      f32x4v cz = *(const f32x4v*)&c_lds[jl + lq4];
      f32x4v az = *(const f32x4v*)&a_lds[jl + lq4];
      float s0 = cz[0] * ev[c][0], s1 = cz[1] * ev[c][1];
      float s2 = cz[2] * ev[c][2], s3 = cz[3] * ev[c][3];
      float run = s0 + s1 + s2 + s3;
      float p1 = s0, p2 = s0 + s1, p3 = s0 + s1 + s2;
      float tot = run;
#pragma unroll
      for (int d = 1; d < 16; d <<= 1){
        float o = __shfl_up(tot, d, 16);
        if (sl >= d) tot += o;
      }
      float excl = tot - run;
      float base = carry + excl;
      carry += __shfl(tot, 15, 16);
      float lg0 = az[0] * ev[c][0] - base;
      float lg1 = az[1] * ev[c][1] - (base + p1);
      float lg2 = az[2] * ev[c][2] - (base + p2);
      float lg3 = az[3] * ev[c][3] - (base + p3);
      if (!guard){
        float cm = fmaxf(fmaxf(lg0, lg1), fmaxf(lg2, lg3));
        if (cm > mOn){ sOn *= __expf(mOn - cm); mOn = cm; }
        sOn += __expf(lg0 - mOn) + __expf(lg1 - mOn) + __expf(lg2 - mOn) + __expf(lg3 - mOn);
        xdot = fmaf(xv[c][0], lg0, xdot);
        xdot = fmaf(xv[c][1], lg1, xdot);
        xdot = fmaf(xv[c][2], lg2, xdot);
        xdot = fmaf(xv[c][3], lg3, xdot);
      } else {
        int nvalid = 2000 - (j0g + lq4);
        float cm = -3.0e38f;
        if (0 < nvalid) cm = fmaxf(cm, lg0);
        if (1 < nvalid) cm = fmaxf(cm, lg1);
        if (2 < nvalid) cm = fmaxf(cm, lg2);
        if (3 < nvalid) cm = fmaxf(cm, lg3);
        if (cm > mOn){ sOn *= __expf(mOn - cm); mOn = cm; }
        if (0 < nvalid){ sOn += __expf(lg0 - mOn); xdot = fmaf(xv[c][0], lg0, xdot); }
        if (1 < nvalid){ sOn += __expf(lg1 - mOn); xdot = fmaf(xv[c][1], lg1, xdot); }
        if (2 < nvalid){ sOn += __expf(lg2 - mOn); xdot = fmaf(xv[c][2], lg2, xdot); }
        if (3 < nvalid){ sOn += __expf(lg3 - mOn); xdot = fmaf(xv[c][3], lg3, xdot); }
      }
#pragma unroll
      for (int u = 0; u < 4; ++u){
        sx += xv[c][u];
        sgl += lutlg[(int)xv[c][u]];
        e2 = fmaf(ev[c][u], ev[c][u], e2);
      }
    }
  }

  // ---- per-split reductions + partial writes (bf16) ----
  xdot = red16(xdot); sx = red16(sx); sgl = red16(sgl); e2 = red16(e2);
#pragma unroll
  for (int d = 1; d < 16; d <<= 1){
    float om = __shfl_xor(mOn, d, 16);
    float os = __shfl_xor(sOn, d, 16);
    float nm = fmaxf(mOn, om);
    sOn = sOn * __expf(mOn - nm) + os * __expf(om - nm);
    mOn = nm;
  }
  __syncthreads();             // all frag reads done before z_l/t_l overlay
  {
    int r0 = (lan >> 4) * 4;
#pragma unroll
    for (int r = 0; r < 4; ++r){
      z_l[r0 + r][bcol] = accz[r];
      t_l[r0 + r][bcol] = acct[r];
    }
  }
  __syncthreads();
  {
    size_t rb = (size_t)(split * 8192 + b0 + lrow) * 64 + lq4;
    f32x4v zv = *(const f32x4v*)&z_l[lrow][lq4];
    f32x4v tv = *(const f32x4v*)&t_l[lrow][lq4];
    union { __bf16 b[4]; unsigned long long q; } pz, pt;
#pragma unroll
    for (int u = 0; u < 4; ++u){ pz.b[u] = (__bf16)zv[u]; pt.b[u] = (__bf16)tv[u]; }
    *(unsigned long long*)&zpart[rb] = pz.q;
    *(unsigned long long*)&tpart[rb] = pt.q;
  }
  if (sl == 0){
    float* so = &scanw[(size_t)(split * 8192 + b0 + lrow) * 8];
    so[0] = carry; so[1] = mOn; so[2] = sOn; so[3] = xdot;
    so[4] = sx; so[5] = sgl; so[6] = e2;
  }
}

// ---- FIXUP: merge 4 splits + quad; LAST block sums part_out -> out --------
__global__ __launch_bounds__(256) void fixup_kernel(const short* __restrict__ zpart,
    const short* __restrict__ tpart, const float* __restrict__ scanw,
    const float* __restrict__ Gws, const float* __restrict__ Minv,
    const float* __restrict__ misc, const float* __restrict__ lss,
    double* __restrict__ part_out, int* __restrict__ cnt,
    float* __restrict__ out)
{
  __shared__ __align__(16) float z_l[16][68];
  __shared__ __align__(16) float t_l[16][68];
  __shared__ double rsum[16];
  __shared__ double dredd[4];
  __shared__ int lastf;
  const int tid = threadIdx.x;
  const int lrow = tid >> 4, sl = tid & 15, lq4 = sl * 4;
  const int b = blockIdx.x * 16 + lrow;

  float z4[4] = {0.f,0.f,0.f,0.f}, t4[4] = {0.f,0.f,0.f,0.f};
#pragma unroll
  for (int s = 0; s < 4; ++s){
    v4s zv = *(const v4s*)&zpart[(size_t)(s * 8192 + b) * 64 + lq4];
    v4s tv = *(const v4s*)&tpart[(size_t)(s * 8192 + b) * 64 + lq4];
#pragma unroll
    for (int u = 0; u < 4; ++u){ z4[u] += bf2f(zv[u]); t4[u] += bf2f(tv[u]); }
  }
#pragma unroll
  for (int u = 0; u < 4; ++u) z_l[lrow][lq4 + u] = z4[u];
  float zz = 0.f, tz = 0.f;
#pragma unroll
  for (int u = 0; u < 4; ++u){ zz = fmaf(z4[u], z4[u], zz); tz = fmaf(t4[u], z4[u], tz); }
  float gz[4] = {0.f, 0.f, 0.f, 0.f};
#pragma unroll 8
  for (int q = 0; q < 64; ++q){
    float zq = z_l[lrow][q];
    f32x4v g = *(const f32x4v*)&Gws[q * 64 + lq4];   // G symmetric; L2-hot
#pragma unroll
    for (int u = 0; u < 4; ++u) gz[u] = fmaf(g[u], zq, gz[u]);
  }
  float zGz = 0.f;
#pragma unroll
  for (int u = 0; u < 4; ++u) zGz = fmaf(z4[u], gz[u], zGz);
  float tk[4];
#pragma unroll
  for (int u = 0; u < 4; ++u){ tk[u] = t4[u] - gz[u]; t_l[lrow][lq4 + u] = tk[u]; }
  float sol[4] = {0.f, 0.f, 0.f, 0.f};
#pragma unroll 8
  for (int q = 0; q < 64; ++q){
    float tq = t_l[lrow][q];
    f32x4v g = *(const f32x4v*)&Minv[q * 64 + lq4];  // Minv symmetric
#pragma unroll
    for (int u = 0; u < 4; ++u) sol[u] = fmaf(g[u], tq, sol[u]);
  }
  float ts = 0.f;
#pragma unroll
  for (int u = 0; u < 4; ++u) ts = fmaf(tk[u], sol[u], ts);

  zz = red16(zz); tz = red16(tz); zGz = red16(zGz); ts = red16(ts);
  if (sl == 0){
    float C = 0.f, M = -3.0e38f, S = 0.f;
    float xdT = 0.f, sxT = 0.f, sglT = 0.f, e2T = 0.f;
#pragma unroll
    for (int s = 0; s < 4; ++s){
      const float* p = &scanw[(size_t)(s * 8192 + b) * 8];
      float mp = p[1] - C;
      float Ss = p[2];
      float mm = fmaxf(M, mp);
      S = S * __expf(M - mm) + Ss * __expf(mp - mm);
      M = mm;
      xdT += p[3] - C * p[4];
      sxT += p[4]; sglT += p[5]; e2T += p[6];
      C += p[0];
    }
    float lse = M + logf(S);
    float mult = lgammaf(sxT + 1.f) - sglT + xdT - sxT * lse;
    float var = expf(lss[0]);
    float logdet = misc[0];
    float diff2 = e2T - 2.f * tz + zGz;
    float quad = diff2 / var - ts / (var * var);
    float lp = -0.5f * (1999.f * LOG2PI_F + logdet + quad) - 0.5f * zz;
    rsum[lrow] = (double)mult + (double)lp;
  }
  __syncthreads();
  if (tid == 0){
    double s = 0.0;
#pragma unroll
    for (int r = 0; r < 16; ++r) s += rsum[r];
    part_out[blockIdx.x] = s;
    __threadfence();
    int old = atomicAdd(&cnt[1], 1);
    lastf = (old == 511);
  }
  __syncthreads();
  if (!lastf) return;
  __threadfence();   // acquire: all part_out writes visible
  // ---- final reduction (fixed order -> deterministic) ----
  double acc = part_out[tid] + part_out[tid + 256];
#pragma unroll
  for (int m = 1; m < 64; m <<= 1) acc += __shfl_xor(acc, m, 64);
  if ((tid & 63) == 0) dredd[tid >> 6] = acc;
  __syncthreads();
  if (tid == 0){
    double tot = dredd[0] + dredd[1] + dredd[2] + dredd[3];
    double mean = tot / 8192.0;
    double loss = -(mean - 0.5 * 64.0 * 1.8378770664093453);
    out[0] = (float)loss;
  }
}

extern "C" void kernel_launch(void* const* d_in, const int* in_sizes, int n_in,
                              void* d_out, int out_size, void* d_ws, size_t ws_size,
                              hipStream_t stream){
  const float* x    = (const float*)d_in[0];
  const float* Psi  = (const float*)d_in[1];
  const float* Wenc = (const float*)d_in[2];
  const float* Wdec = (const float*)d_in[3];
  const float* vlv  = (const float*)d_in[4];
  const float* lss  = (const float*)d_in[5];
  const float* eta  = (const float*)d_in[6];
  float* ws = (float*)d_ws;
  float*  a_ws  = ws + OFF_A;
  float*  c_ws  = ws + OFF_C;
  float*  Gws   = ws + OFF_G;
  float*  Minv  = ws + OFF_MINV;
  float*  misc  = ws + OFF_MISC;
  short*  wfrag = (short*)(ws + OFF_WFRAG);
  float*  gpart = ws + OFF_GPART;   // aliases zpart region (dead until mega)
  short*  zpart = (short*)(ws + OFF_ZPART);
  short*  tpart = (short*)(ws + OFF_TPART);
  float*  scanw = ws + OFF_SCAN;
  double* partw = (double*)(ws + OFF_PART);
  int*    cntw  = (int*)(ws + OFF_CNT);

  prep2_kernel<<<104, 256, 0, stream>>>(Psi, Wenc, Wdec, a_ws, c_ws, wfrag, gpart, cntw);
  gramneu_kernel<<<16, 256, 0, stream>>>(gpart, vlv, lss, Gws, Minv, misc, cntw);
  mega_kernel<<<2048, 256, 0, stream>>>(x, eta, wfrag, a_ws, c_ws, zpart, tpart, scanw);
  fixup_kernel<<<512, 256, 0, stream>>>(zpart, tpart, scanw, Gws, Minv, misc, lss,
                                        partw, cntw, (float*)d_out);
}

// Round 21
// 79.772 us; speedup vs baseline: 1.1358x; 1.1358x over previous
//
#include <hip/hip_runtime.h>
#include <math.h>

// LinearCatVAE loss on MI355X.
// Psi = Helmert basis => Psi products are diag + prefix scans.
// R16/R18 (79.9us, best, reproduced twice): burst mega (1 barrier, W-frag
// stream, bf16 partials), split-4, 6 launches.
// R19 (90.6us, reverted): last-block ticket fusion -- in-dispatch
// serialization of neumann/final-reduce tails cost more than the launch
// gaps they replaced. R20 = R18 verbatim (best-known configuration).

#define LOG2PI_F 1.8378770664093453f

typedef short  v8s    __attribute__((ext_vector_type(8)));
typedef short  v4s    __attribute__((ext_vector_type(4)));
typedef float  f32x4v __attribute__((ext_vector_type(4)));
typedef float  f32x4u __attribute__((ext_vector_type(4), aligned(4)));
typedef float  f32x2u __attribute__((ext_vector_type(2), aligned(4)));

// ---- workspace offsets (floats) ----
#define OFF_A     0          // 2048
#define OFF_C     2048       // 2048
#define OFF_G     4096       // 4096
#define OFF_MINV  8192       // 4096
#define OFF_MISC  12288      // 64
#define OFF_WFRAG 12352      // 131072 (512KB: 32 sc x 4 planes x 256 tid x 8 bf16)
#define OFF_ZPART 143424     // bf16 4*8192*64 = 2097152 bf16 = 1048576 float-slots
#define OFF_GPART OFF_ZPART  // alias: gpart (131072 floats) dead before mega
#define OFF_TPART 1192000    // 1048576 float-slots
#define OFF_SCAN  2240576    // 262144
#define OFF_PART  2502720    // 512 doubles = 1024 floats
#define OFF_END   2503744    // ~10 MB

__device__ inline float red16(float v){
#pragma unroll
  for (int m = 1; m < 16; m <<= 1) v += __shfl_xor(v, m, 16);
  return v;
}
__device__ inline float bf2f(short s){
  union { unsigned u; float f; } v;
  v.u = ((unsigned)(unsigned short)s) << 16;
  return v.f;
}

// ------- PREP2 (fused): 0-63 wenceff->frags, 64-95 wdtgram->frags+gpart,
//                        96-103 coef (a/c tables for mega) -------------------
__global__ __launch_bounds__(256) void prep2_kernel(const float* __restrict__ Psi,
    const float* __restrict__ Wenc, const float* __restrict__ Wdec,
    float* __restrict__ a_ws, float* __restrict__ c_ws,
    short* __restrict__ fr, float* __restrict__ gparts){
  __shared__ __align__(16) float shm[64 * 68];
  const int tid = threadIdx.x;
  const int blk = blockIdx.x;
  if (blk >= 96){
    // coef: a[e]=Psi[e][e], c[e]=-Psi[e][e+1]
    int e = (blk - 96) * 256 + tid;
    float a = 0.f, c = 0.f;
    if (e < 1999){
      f32x2u v = *(const f32x2u*)(Psi + (size_t)e * 2001);
      a = v[0]; c = -v[1];
    }
    a_ws[e] = a;
    c_ws[e] = c;
    return;
  }
  if (blk < 64){
    // wenceff: row k of Wenc@Psi via exclusive scan; write frag planes 0/1
    float* scan = shm;
    const int k = blk;
    const float* wrow = Wenc + (size_t)k * 1999;
    int base = tid * 8;
    float w[8], sloc[8], av[8], cv[8];
    float run = 0.f;
#pragma unroll
    for (int u = 0; u < 8; ++u){
      int e = base + u;
      bool valid = (e < 1999);
      float wv = valid ? wrow[e] : 0.f;
      if (valid){
        f32x2u v = *(const f32x2u*)(Psi + (size_t)e * 2001);
        av[u] = v[0]; cv[u] = -v[1];
      } else { av[u] = 0.f; cv[u] = 0.f; }
      w[u] = wv;
      sloc[u] = run;
      run += cv[u] * wv;
    }
    scan[tid] = run;
    __syncthreads();
    for (int off = 1; off < 256; off <<= 1){
      float y = (tid >= off) ? scan[tid - off] : 0.f;
      __syncthreads();
      scan[tid] += y;
      __syncthreads();
    }
    float excl = scan[tid] - run;
    union { __bf16 b[8]; v8s s; } pk;
#pragma unroll
    for (int u = 0; u < 8; ++u){
      int e = base + u;
      float val = (e < 2000) ? (av[u] * w[u] - (excl + sloc[u])) : 0.f;
      pk.b[u] = (__bf16)val;
    }
    // frag dest: base -> sc, khalf, kg; tid_m encodes (bcol=k, kg)
    int sc = base >> 6;
    int r  = base & 63;
    int kh = r >> 5;
    int kg = r & 31;
    int tid_m = ((k >> 4) << 6) | ((kg >> 3) << 4) | (k & 15);
    *(v8s*)(fr + (size_t)sc * 8192 + kh * 2048 + tid_m * 8) = pk.s;
    return;
  }
  // wdtgram: chunk sc of Wdec -> frag planes 2/3 + gram partial
  auto Ws = (float(*)[68])shm;
  const int sc = blk - 64;
  const int j0 = sc * 64;
#pragma unroll
  for (int i = 0; i < 16; ++i){
    int e = tid + i * 256;
    int j = e >> 6, kk = e & 63;
    Ws[j][kk] = (j0 + j < 1999) ? Wdec[(size_t)(j0 + j) * 64 + kk] : 0.f;
  }
  __syncthreads();
  {
    const int bcol = ((tid >> 6) << 4) | (tid & 15);
    const int kg = ((tid >> 4) & 3) * 8;
    union { __bf16 b[8]; v8s s; } p2, p3;
#pragma unroll
    for (int u = 0; u < 8; ++u){
      p2.b[u] = (__bf16)Ws[kg + u][bcol];
      p3.b[u] = (__bf16)Ws[32 + kg + u][bcol];
    }
    short* o = fr + (size_t)sc * 8192 + tid * 8;
    *(v8s*)(o + 4096) = p2.s;
    *(v8s*)(o + 6144) = p3.s;
  }
  int p = tid & 63;
  int qb = (tid >> 6) * 16;
  float acc[16] = {};
  for (int jj = 0; jj < 64; ++jj){
    float wp = Ws[jj][p];
    const float4 q0 = *(const float4*)&Ws[jj][qb];
    const float4 q1 = *(const float4*)&Ws[jj][qb + 4];
    const float4 q2 = *(const float4*)&Ws[jj][qb + 8];
    const float4 q3 = *(const float4*)&Ws[jj][qb + 12];
    acc[0]  = fmaf(wp, q0.x, acc[0]);  acc[1]  = fmaf(wp, q0.y, acc[1]);
    acc[2]  = fmaf(wp, q0.z, acc[2]);  acc[3]  = fmaf(wp, q0.w, acc[3]);
    acc[4]  = fmaf(wp, q1.x, acc[4]);  acc[5]  = fmaf(wp, q1.y, acc[5]);
    acc[6]  = fmaf(wp, q1.z, acc[6]);  acc[7]  = fmaf(wp, q1.w, acc[7]);
    acc[8]  = fmaf(wp, q2.x, acc[8]);  acc[9]  = fmaf(wp, q2.y, acc[9]);
    acc[10] = fmaf(wp, q2.z, acc[10]); acc[11] = fmaf(wp, q2.w, acc[11]);
    acc[12] = fmaf(wp, q3.x, acc[12]); acc[13] = fmaf(wp, q3.y, acc[13]);
    acc[14] = fmaf(wp, q3.z, acc[14]); acc[15] = fmaf(wp, q3.w, acc[15]);
  }
  float* gp = gparts + (size_t)sc * 4096 + (size_t)p * 64 + qb;
#pragma unroll
  for (int u = 0; u < 4; ++u){
    float4 o; o.x = acc[4*u]; o.y = acc[4*u+1]; o.z = acc[4*u+2]; o.w = acc[4*u+3];
    *(float4*)&gp[4*u] = o;
  }
}

// ---------------- P2b: reduce 32 partial grams -> G ----------------
__global__ __launch_bounds__(256) void gram_reduce_kernel(const float* __restrict__ gparts,
                                                          float* __restrict__ G){
  int e = blockIdx.x * 256 + threadIdx.x;   // 16 blocks
  float s = 0.f;
#pragma unroll
  for (int p = 0; p < 32; ++p) s += gparts[(size_t)p * 4096 + e];
  G[e] = s;
}

// ---- P3: Minv + logdet (Neumann truncated at A^2); G read coalesced ----
__global__ __launch_bounds__(256) void neumann_kernel(const float* __restrict__ Gws,
    const float* __restrict__ vlv, const float* __restrict__ lss,
    float* __restrict__ Minv, float* __restrict__ misc){
  __shared__ float As[64][65];
  __shared__ float A2s[64][65];
  __shared__ double dred[4][3];
  int tid = threadIdx.x;
  float var = expf(lss[0]);
  for (int e = tid; e < 4096; e += 256){
    int i = e >> 6;
    As[i][e & 63] = expf(vlv[i]) * Gws[e] / var;
  }
  __syncthreads();
  for (int e = tid; e < 4096; e += 256){
    int i = e >> 6, j = e & 63;
    float s = 0.f;
    for (int q = 0; q < 64; ++q) s = fmaf(As[i][q], As[q][j], s);
    A2s[i][j] = s;
  }
  __syncthreads();
  double t1 = 0, t2 = 0, t3 = 0;
  for (int e = tid; e < 4096; e += 256){
    int i = e >> 6, j = e & 63;
    if (i == j){ t1 += (double)As[i][i]; t2 += (double)A2s[i][i]; }
    t3 += (double)A2s[i][j] * (double)As[j][i];
  }
#pragma unroll
  for (int m = 1; m < 64; m <<= 1){
    t1 += __shfl_xor(t1, m, 64); t2 += __shfl_xor(t2, m, 64); t3 += __shfl_xor(t3, m, 64);
  }
  int wid = tid >> 6;
  if ((tid & 63) == 0){ dred[wid][0] = t1; dred[wid][1] = t2; dred[wid][2] = t3; }
  __syncthreads();
  for (int e = tid; e < 4096; e += 256){
    int i = e >> 6, j = e & 63;
    float v = ((i == j) ? 1.f : 0.f) - As[i][j] + A2s[i][j];
    Minv[e] = v * expf(vlv[j]);
  }
  if (tid == 0){
    double tr1 = 0, tr2 = 0, tr3 = 0;
    for (int w2 = 0; w2 < 4; ++w2){
      tr1 += dred[w2][0]; tr2 += dred[w2][1]; tr3 += dred[w2][2];
    }
    misc[0] = (float)(1999.0 * (double)lss[0] + tr1 - tr2 / 2.0 + tr3 / 3.0);
  }
}

// ---------------- MEGA "burst": whole-tile stage, ONE barrier --------------
// 2048 blocks x 256 threads; split = bid&3 (8 chunks of 64 cols);
// rowblk = bid>>2 -> 16 rows. LDS ~38KB -> 4 blocks/CU natural.
__global__ __launch_bounds__(256) void mega_kernel(
    const float* __restrict__ x, const float* __restrict__ eta,
    const short* __restrict__ wfrag,
    const float* __restrict__ a_ws, const float* __restrict__ c_ws,
    short* __restrict__ zpart, short* __restrict__ tpart,
    float* __restrict__ scanw)
{
  __shared__ float lutlg[128];
  __shared__ __align__(16) float a_lds[512];
  __shared__ __align__(16) float c_lds[512];
  __shared__ __align__(16) __bf16 At[16][520];   // 1040B row stride
  __shared__ __align__(16) __bf16 Ae[16][520];
  auto z_l = (float(*)[68])((unsigned char*)At);             // epilogue overlay
  auto t_l = (float(*)[68])((unsigned char*)At + 4352);

  const int tid = threadIdx.x;
  const int split = blockIdx.x & 3;
  const int rowblk = blockIdx.x >> 2;
  const int b0 = rowblk * 16;
  const int ch0 = split * 8;
  const int cb0 = split * 512;
  if (tid < 128) lutlg[tid] = lgammaf((float)(tid + 1));
  for (int i = tid; i < 512; i += 256){ a_lds[i] = a_ws[cb0 + i]; c_lds[i] = c_ws[cb0 + i]; }

  const int lrow = tid >> 4;
  const int sl   = tid & 15;
  const int lq4  = sl * 4;
  const int wid  = tid >> 6, lan = tid & 63;
  const int arow = lan & 15;
  const int bcol = wid * 16 + (lan & 15);
  const int kgrp = (lan >> 4) * 8;

  f32x4v accz = {0.f, 0.f, 0.f, 0.f}, acct = {0.f, 0.f, 0.f, 0.f};
  float carry = 0.f, mOn = -3.0e38f, sOn = 0.f;
  float xdot = 0.f, sx = 0.f, sgl = 0.f, e2 = 0.f;

  const float* xs_base = x   + (size_t)(b0 + lrow) * 2000 + cb0 + lq4;
  const float* es_base = eta + (size_t)(b0 + lrow) * 1999 + cb0 + lq4;
  const short* fr_base = wfrag + (size_t)ch0 * 8192 + (size_t)tid * 8;
  const bool lastSplit = (split == 3);

  // ---- burst-load all 8 chunks of x and eta (all loads in flight) ----
  float xv[8][4], ev[8][4];
#pragma unroll
  for (int c = 0; c < 8; ++c){
    const float* xp = xs_base + c * 64;
    if (!(lastSplit && c == 7)){
      f32x4v v = *(const f32x4v*)xp;
      xv[c][0] = v[0]; xv[c][1] = v[1]; xv[c][2] = v[2]; xv[c][3] = v[3];
    } else {
#pragma unroll
      for (int u = 0; u < 4; ++u){
        int cc = cb0 + c * 64 + lq4 + u;
        xv[c][u] = (cc < 2000) ? xp[u] : 0.f;
      }
    }
  }
#pragma unroll
  for (int c = 0; c < 8; ++c){
    const float* ep = es_base + c * 64;
    if (!(lastSplit && c == 7)){
      f32x4u v = *(const f32x4u*)ep;
      ev[c][0] = v[0]; ev[c][1] = v[1]; ev[c][2] = v[2]; ev[c][3] = v[3];
    } else {
#pragma unroll
      for (int u = 0; u < 4; ++u){
        int cc = cb0 + c * 64 + lq4 + u;
        ev[c][u] = (cc < 1999) ? ep[u] : 0.f;
      }
    }
  }
  v8s WF0[2], WF1[2], WD0[2], WD1[2];
  {
    const short* fb = fr_base;
    WF0[0] = *(const v8s*)(fb);
    WF1[0] = *(const v8s*)(fb + 2048);
    WD0[0] = *(const v8s*)(fb + 4096);
    WD1[0] = *(const v8s*)(fb + 6144);
  }
  // ---- convert + stage whole tile ----
#pragma unroll
  for (int c = 0; c < 8; ++c){
    union { __bf16 b[4]; unsigned long long q; } cx, ce;
#pragma unroll
    for (int u = 0; u < 4; ++u){
      cx.b[u] = (__bf16)__logf(xv[c][u] + 1.f);
      ce.b[u] = (__bf16)ev[c][u];
    }
    *(unsigned long long*)&At[lrow][c * 64 + lq4] = cx.q;
    *(unsigned long long*)&Ae[lrow][c * 64 + lq4] = ce.q;
  }
  __syncthreads();   // the ONLY staging barrier

  // ---- 8 barrier-free chunk steps ----
#pragma unroll
  for (int c = 0; c < 8; ++c){
    if (c + 1 < 8){
      const short* fb = fr_base + (size_t)(c + 1) * 8192;
      WF0[(c + 1) & 1] = *(const v8s*)(fb);
      WF1[(c + 1) & 1] = *(const v8s*)(fb + 2048);
      WD0[(c + 1) & 1] = *(const v8s*)(fb + 4096);
      WD1[(c + 1) & 1] = *(const v8s*)(fb + 6144);
    }
    {
      const int cb = c * 64;
      v8s ax0 = *(const v8s*)&At[arow][cb + kgrp];
      v8s ax1 = *(const v8s*)&At[arow][cb + 32 + kgrp];
      v8s ae0 = *(const v8s*)&Ae[arow][cb + kgrp];
      v8s ae1 = *(const v8s*)&Ae[arow][cb + 32 + kgrp];
      accz = __builtin_amdgcn_mfma_f32_16x16x32_bf16(ax0, WF0[c & 1], accz, 0, 0, 0);
      accz = __builtin_amdgcn_mfma_f32_16x16x32_bf16(ax1, WF1[c & 1], accz, 0, 0, 0);
      acct = __builtin_amdgcn_mfma_f32_16x16x32_bf16(ae0, WD0[c & 1], acct, 0, 0, 0);
      acct = __builtin_amdgcn_mfma_f32_16x16x32_bf16(ae1, WD1[c & 1], acct, 0, 0, 0);
    }
    {
      const int j0g = (ch0 + c) * 64;
      const int jl  = c * 64;
      const bool guard = lastSplit && (c == 7);
      f32x4v cz = *(const f32x4v*)&c_lds[jl + lq4];
      f32x4v az = *(const f32x4v*)&a_lds[jl + lq4];
      float s0 = cz[0] * ev[c][0], s1 = cz[1] * ev[c][1];
      float s2 = cz[2] * ev[c][2], s3 = cz[3] * ev[c][3];
      float run = s0 + s1 + s2 + s3;
      float p1 = s0, p2 = s0 + s1, p3 = s0 + s1 + s2;
      float tot = run;
#pragma unroll
      for (int d = 1; d < 16; d <<= 1){
        float o = __shfl_up(tot, d, 16);
        if (sl >= d) tot += o;
      }
      float excl = tot - run;
      float base = carry + excl;
      carry += __shfl(tot, 15, 16);
      float lg0 = az[0] * ev[c][0] - base;
      float lg1 = az[1] * ev[c][1] - (base + p1);
      float lg2 = az[2] * ev[c][2] - (base + p2);
      float lg3 = az[3] * ev[c][3] - (base + p3);
      if (!guard){
        float cm = fmaxf(fmaxf(lg0, lg1), fmaxf(lg2, lg3));
        if (cm > mOn){ sOn *= __expf(mOn - cm); mOn = cm; }
        sOn += __expf(lg0 - mOn) + __expf(lg1 - mOn) + __expf(lg2 - mOn) + __expf(lg3 - mOn);
        xdot = fmaf(xv[c][0], lg0, xdot);
        xdot = fmaf(xv[c][1], lg1, xdot);
        xdot = fmaf(xv[c][2], lg2, xdot);
        xdot = fmaf(xv[c][3], lg3, xdot);
      } else {
        int nvalid = 2000 - (j0g + lq4);
        float cm = -3.0e38f;
        if (0 < nvalid) cm = fmaxf(cm, lg0);
        if (1 < nvalid) cm = fmaxf(cm, lg1);
        if (2 < nvalid) cm = fmaxf(cm, lg2);
        if (3 < nvalid) cm = fmaxf(cm, lg3);
        if (cm > mOn){ sOn *= __expf(mOn - cm); mOn = cm; }
        if (0 < nvalid){ sOn += __expf(lg0 - mOn); xdot = fmaf(xv[c][0], lg0, xdot); }
        if (1 < nvalid){ sOn += __expf(lg1 - mOn); xdot = fmaf(xv[c][1], lg1, xdot); }
        if (2 < nvalid){ sOn += __expf(lg2 - mOn); xdot = fmaf(xv[c][2], lg2, xdot); }
        if (3 < nvalid){ sOn += __expf(lg3 - mOn); xdot = fmaf(xv[c][3], lg3, xdot); }
      }
#pragma unroll
      for (int u = 0; u < 4; ++u){
        sx += xv[c][u];
        sgl += lutlg[(int)xv[c][u]];
        e2 = fmaf(ev[c][u], ev[c][u], e2);
      }
    }
  }

  // ---- per-split reductions + partial writes (bf16) ----
  xdot = red16(xdot); sx = red16(sx); sgl = red16(sgl); e2 = red16(e2);
#pragma unroll
  for (int d = 1; d < 16; d <<= 1){
    float om = __shfl_xor(mOn, d, 16);
    float os = __shfl_xor(sOn, d, 16);
    float nm = fmaxf(mOn, om);
    sOn = sOn * __expf(mOn - nm) + os * __expf(om - nm);
    mOn = nm;
  }
  __syncthreads();             // all frag reads done before z_l/t_l overlay
  {
    int r0 = (lan >> 4) * 4;
#pragma unroll
    for (int r = 0; r < 4; ++r){
      z_l[r0 + r][bcol] = accz[r];
      t_l[r0 + r][bcol] = acct[r];
    }
  }
  __syncthreads();
  {
    size_t rb = (size_t)(split * 8192 + b0 + lrow) * 64 + lq4;
    f32x4v zv = *(const f32x4v*)&z_l[lrow][lq4];
    f32x4v tv = *(const f32x4v*)&t_l[lrow][lq4];
    union { __bf16 b[4]; unsigned long long q; } pz, pt;
#pragma unroll
    for (int u = 0; u < 4; ++u){ pz.b[u] = (__bf16)zv[u]; pt.b[u] = (__bf16)tv[u]; }
    *(unsigned long long*)&zpart[rb] = pz.q;
    *(unsigned long long*)&tpart[rb] = pt.q;
  }
  if (sl == 0){
    float* so = &scanw[(size_t)(split * 8192 + b0 + lrow) * 8];
    so[0] = carry; so[1] = mOn; so[2] = sOn; so[3] = xdot;
    so[4] = sx; so[5] = sgl; so[6] = e2;
  }
}

// ---------------- FIXUP: merge 4 splits + quad; block-sum to double --------
__global__ __launch_bounds__(256) void fixup_kernel(const short* __restrict__ zpart,
    const short* __restrict__ tpart, const float* __restrict__ scanw,
    const float* __restrict__ Gws, const float* __restrict__ Minv,
    const float* __restrict__ misc, const float* __restrict__ lss,
    double* __restrict__ part_out)
{
  __shared__ __align__(16) float z_l[16][68];
  __shared__ __align__(16) float t_l[16][68];
  __shared__ double rsum[16];
  const int tid = threadIdx.x;
  const int lrow = tid >> 4, sl = tid & 15, lq4 = sl * 4;
  const int b = blockIdx.x * 16 + lrow;

  float z4[4] = {0.f,0.f,0.f,0.f}, t4[4] = {0.f,0.f,0.f,0.f};
#pragma unroll
  for (int s = 0; s < 4; ++s){
    v4s zv = *(const v4s*)&zpart[(size_t)(s * 8192 + b) * 64 + lq4];
    v4s tv = *(const v4s*)&tpart[(size_t)(s * 8192 + b) * 64 + lq4];
#pragma unroll
    for (int u = 0; u < 4; ++u){ z4[u] += bf2f(zv[u]); t4[u] += bf2f(tv[u]); }
  }
#pragma unroll
  for (int u = 0; u < 4; ++u) z_l[lrow][lq4 + u] = z4[u];
  float zz = 0.f, tz = 0.f;
#pragma unroll
  for (int u = 0; u < 4; ++u){ zz = fmaf(z4[u], z4[u], zz); tz = fmaf(t4[u], z4[u], tz); }
  float gz[4] = {0.f, 0.f, 0.f, 0.f};
#pragma unroll 8
  for (int q = 0; q < 64; ++q){
    float zq = z_l[lrow][q];
    f32x4v g = *(const f32x4v*)&Gws[q * 64 + lq4];   // G symmetric; L2-hot
#pragma unroll
    for (int u = 0; u < 4; ++u) gz[u] = fmaf(g[u], zq, gz[u]);
  }
  float zGz = 0.f;
#pragma unroll
  for (int u = 0; u < 4; ++u) zGz = fmaf(z4[u], gz[u], zGz);
  float tk[4];
#pragma unroll
  for (int u = 0; u < 4; ++u){ tk[u] = t4[u] - gz[u]; t_l[lrow][lq4 + u] = tk[u]; }
  float sol[4] = {0.f, 0.f, 0.f, 0.f};
#pragma unroll 8
  for (int q = 0; q < 64; ++q){
    float tq = t_l[lrow][q];
    f32x4v g = *(const f32x4v*)&Minv[q * 64 + lq4];  // Minv symmetric
#pragma unroll
    for (int u = 0; u < 4; ++u) sol[u] = fmaf(g[u], tq, sol[u]);
  }
  float ts = 0.f;
#pragma unroll
  for (int u = 0; u < 4; ++u) ts = fmaf(tk[u], sol[u], ts);

  zz = red16(zz); tz = red16(tz); zGz = red16(zGz); ts = red16(ts);
  if (sl == 0){
    float C = 0.f, M = -3.0e38f, S = 0.f;
    float xdT = 0.f, sxT = 0.f, sglT = 0.f, e2T = 0.f;
#pragma unroll
    for (int s = 0; s < 4; ++s){
      const float* p = &scanw[(size_t)(s * 8192 + b) * 8];
      float mp = p[1] - C;
      float Ss = p[2];
      float mm = fmaxf(M, mp);
      S = S * __expf(M - mm) + Ss * __expf(mp - mm);
      M = mm;
      xdT += p[3] - C * p[4];
      sxT += p[4]; sglT += p[5]; e2T += p[6];
      C += p[0];
    }
    float lse = M + logf(S);
    float mult = lgammaf(sxT + 1.f) - sglT + xdT - sxT * lse;
    float var = expf(lss[0]);
    float logdet = misc[0];
    float diff2 = e2T - 2.f * tz + zGz;
    float quad = diff2 / var - ts / (var * var);
    float lp = -0.5f * (1999.f * LOG2PI_F + logdet + quad) - 0.5f * zz;
    rsum[lrow] = (double)mult + (double)lp;
  }
  __syncthreads();
  if (tid == 0){
    double s = 0.0;
#pragma unroll
    for (int r = 0; r < 16; ++r) s += rsum[r];
    part_out[blockIdx.x] = s;
  }
}

// ---------------- Z: final mean + constants ----------------
__global__ __launch_bounds__(256) void reduce_kernel(const double* __restrict__ part,
                                                     float* __restrict__ out){
  __shared__ double red[4];
  int tid = threadIdx.x;
  double acc = part[tid] + part[tid + 256];
#pragma unroll
  for (int m = 1; m < 64; m <<= 1) acc += __shfl_xor(acc, m, 64);
  if ((tid & 63) == 0) red[tid >> 6] = acc;
  __syncthreads();
  if (tid == 0){
    double tot = red[0] + red[1] + red[2] + red[3];
    double mean = tot / 8192.0;
    double loss = -(mean - 0.5 * 64.0 * 1.8378770664093453);
    out[0] = (float)loss;
  }
}

extern "C" void kernel_launch(void* const* d_in, const int* in_sizes, int n_in,
                              void* d_out, int out_size, void* d_ws, size_t ws_size,
                              hipStream_t stream){
  const float* x    = (const float*)d_in[0];
  const float* Psi  = (const float*)d_in[1];
  const float* Wenc = (const float*)d_in[2];
  const float* Wdec = (const float*)d_in[3];
  const float* vlv  = (const float*)d_in[4];
  const float* lss  = (const float*)d_in[5];
  const float* eta  = (const float*)d_in[6];
  float* ws = (float*)d_ws;
  float*  a_ws  = ws + OFF_A;
  float*  c_ws  = ws + OFF_C;
  float*  Gws   = ws + OFF_G;
  float*  Minv  = ws + OFF_MINV;
  float*  misc  = ws + OFF_MISC;
  short*  wfrag = (short*)(ws + OFF_WFRAG);
  float*  gpart = ws + OFF_GPART;   // aliases zpart region (dead until mega)
  short*  zpart = (short*)(ws + OFF_ZPART);
  short*  tpart = (short*)(ws + OFF_TPART);
  float*  scanw = ws + OFF_SCAN;
  double* partw = (double*)(ws + OFF_PART);

  prep2_kernel<<<104, 256, 0, stream>>>(Psi, Wenc, Wdec, a_ws, c_ws, wfrag, gpart);
  gram_reduce_kernel<<<16, 256, 0, stream>>>(gpart, Gws);
  neumann_kernel<<<1, 256, 0, stream>>>(Gws, vlv, lss, Minv, misc);
  mega_kernel<<<2048, 256, 0, stream>>>(x, eta, wfrag, a_ws, c_ws, zpart, tpart, scanw);
  fixup_kernel<<<512, 256, 0, stream>>>(zpart, tpart, scanw, Gws, Minv, misc, lss, partw);
  reduce_kernel<<<1, 256, 0, stream>>>(partw, (float*)d_out);
}